// Round 1
// baseline (185.589 us; speedup 1.0000x reference)
//
#include <hip/hip_runtime.h>

typedef float f32x4 __attribute__((ext_vector_type(4)));
typedef short short8 __attribute__((ext_vector_type(8)));

#define N_TOT 1024
#define N_HALF 512
#define D 64
#define KPOOL 256

__device__ __forceinline__ short f2bf(float v) {
    unsigned u = __float_as_uint(v);
    u += 0x7FFFu + ((u >> 16) & 1u);   // round-to-nearest-even
    return (short)(u >> 16);
}

__device__ __forceinline__ float tanh_fast(float x) {
    float e = __expf(2.f * x);
    return 1.f - 2.f / (e + 1.f);
}

// ---------------- Kernel 1: x = concat(x1@W1+b1, x2@W2+b2), fp32 + bf16 copies
__global__ void k_proj(const float* __restrict__ x1, const float* __restrict__ x2,
                       const float* __restrict__ W1, const float* __restrict__ b1,
                       const float* __restrict__ W2, const float* __restrict__ b2,
                       float* __restrict__ x_f, unsigned short* __restrict__ x_bf) {
    int r = blockIdx.x;               // 0..2047 (b*1024 + n)
    int b = r >> 10, n = r & 1023;
    const float *src, *W, *bias;
    if (n < N_HALF) { src = x1 + (b * N_HALF + n) * D;            W = W1; bias = b1; }
    else            { src = x2 + (b * N_HALF + (n - N_HALF)) * D; W = W2; bias = b2; }
    __shared__ float row[D];
    int t = threadIdx.x;
    row[t] = src[t];
    __syncthreads();
    float acc = bias[t];
#pragma unroll
    for (int d = 0; d < D; ++d) acc = fmaf(row[d], W[d * D + t], acc);
    x_f[r * D + t] = acc;
    x_bf[r * D + t] = (unsigned short)f2bf(acc);
}

// ---------------- Kernel 2: per (b,i): scores over all j, softmax, agg, out-proj
__global__ void __launch_bounds__(256)
k_attn(const float* __restrict__ x_f, const unsigned short* __restrict__ x_bf,
       const float* __restrict__ Wa, const float* __restrict__ ba,
       const float* __restrict__ w11, const float* __restrict__ w22,
       const float* __restrict__ w12,
       const float* __restrict__ Wpa, const float* __restrict__ bpa,
       const float* __restrict__ Wwoa, const float* __restrict__ bwoa,
       float* __restrict__ xo_pre) {
    int bid = blockIdx.x;             // 0..2047
    int b = bid >> 10, i = bid & 1023;
    int tid = threadIdx.x;
    int l = tid & 63, wv = tid >> 6;
    int kc = l & 15, dg = l >> 4;

    __shared__ float xi_s[D];
    __shared__ float ssc[N_TOT];
    __shared__ float red[256];
    __shared__ float aggred[4][D];
    __shared__ float aggv[D];

    if (tid < D) xi_s[tid] = x_f[(b * N_TOT + i) * D + tid];
    __syncthreads();

    // Build B fragments: B[d][k] = x_i[d] * Wa[d][k], bf16, lane holds col kc of k-tile kt,
    // 8 contiguous d at dg*8 (+32 for second K-step).
    const float* wvecA = (i < N_HALF) ? w11 : w12;
    const float* wvecB = (i < N_HALF) ? w12 : w22;
    short8 bfrag[4][2];
    float ba_f[4], wAf[4], wBf[4];
#pragma unroll
    for (int kt = 0; kt < 4; ++kt) {
        int kcol = kt * 16 + kc;
        ba_f[kt] = ba[kcol];
        wAf[kt] = wvecA[kcol];
        wBf[kt] = wvecB[kcol];
#pragma unroll
        for (int m = 0; m < 2; ++m) {
            short8 f;
#pragma unroll
            for (int e = 0; e < 8; ++e) {
                int d = m * 32 + dg * 8 + e;
                f[e] = f2bf(xi_s[d] * Wa[d * D + kcol]);
            }
            bfrag[kt][m] = f;
        }
    }

    // GEMM over j-tiles: t_pre(16j x 64k) per tile, tanh, dot with w, reduce -> s[j]
    const unsigned short* xb_b = x_bf + b * N_TOT * D;
    for (int jt = wv; jt < 64; jt += 4) {
        const unsigned short* arow = xb_b + (jt * 16 + kc) * D + dg * 8;
        short8 a0 = *reinterpret_cast<const short8*>(arow);
        short8 a1 = *reinterpret_cast<const short8*>(arow + 32);
        f32x4 acc[4];
#pragma unroll
        for (int kt = 0; kt < 4; ++kt) {
            f32x4 z = {0.f, 0.f, 0.f, 0.f};
            z = __builtin_amdgcn_mfma_f32_16x16x32_bf16(a0, bfrag[kt][0], z, 0, 0, 0);
            z = __builtin_amdgcn_mfma_f32_16x16x32_bf16(a1, bfrag[kt][1], z, 0, 0, 0);
            acc[kt] = z;
        }
        bool useA = (jt < 32);   // j < 512
#pragma unroll
        for (int r = 0; r < 4; ++r) {
            float part = 0.f;
#pragma unroll
            for (int kt = 0; kt < 4; ++kt) {
                float wv_ = useA ? wAf[kt] : wBf[kt];
                part += wv_ * tanh_fast(acc[kt][r] + ba_f[kt]);
            }
            part += __shfl_xor(part, 1);
            part += __shfl_xor(part, 2);
            part += __shfl_xor(part, 4);
            part += __shfl_xor(part, 8);
            if (kc == 0) ssc[jt * 16 + dg * 4 + r] = part;
        }
    }
    __syncthreads();

    // softmax over j (1024)
    float lm = -1e30f;
#pragma unroll
    for (int c = 0; c < 4; ++c) lm = fmaxf(lm, ssc[tid + 256 * c]);
    red[tid] = lm;
    __syncthreads();
    for (int s = 128; s > 0; s >>= 1) {
        if (tid < s) red[tid] = fmaxf(red[tid], red[tid + s]);
        __syncthreads();
    }
    float smax = red[0];
    __syncthreads();
    float ls = 0.f;
#pragma unroll
    for (int c = 0; c < 4; ++c) {
        int j = tid + 256 * c;
        float e = __expf(ssc[j] - smax);
        ssc[j] = e;
        ls += e;
    }
    red[tid] = ls;
    __syncthreads();
    for (int s = 128; s > 0; s >>= 1) {
        if (tid < s) red[tid] += red[tid + s];
        __syncthreads();
    }
    float denom = red[0];

    // agg[d] = sum_j att[j] * x[j][d]   (fp32, X from L2)
    int d = tid & 63, c = tid >> 6;
    const float* xf_b = x_f + b * N_TOT * D;
    float a0 = 0.f, a1 = 0.f, a2 = 0.f, a3 = 0.f;
    int j0 = c * 256;
    for (int jj = 0; jj < 256; jj += 4) {
        a0 = fmaf(ssc[j0 + jj],     xf_b[(j0 + jj) * D + d],     a0);
        a1 = fmaf(ssc[j0 + jj + 1], xf_b[(j0 + jj + 1) * D + d], a1);
        a2 = fmaf(ssc[j0 + jj + 2], xf_b[(j0 + jj + 2) * D + d], a2);
        a3 = fmaf(ssc[j0 + jj + 3], xf_b[(j0 + jj + 3) * D + d], a3);
    }
    aggred[c][d] = (a0 + a1) + (a2 + a3);
    __syncthreads();
    if (tid < D)
        aggv[tid] = (aggred[0][tid] + aggred[1][tid] + aggred[2][tid] + aggred[3][tid]) / denom;
    __syncthreads();

    // xo = agg@Wpa + bpa + x_i@Wwoa + bwoa
    if (tid < D) {
        int k = tid;
        float acc = bpa[k] + bwoa[k];
#pragma unroll 8
        for (int dd = 0; dd < D; ++dd)
            acc += aggv[dd] * Wpa[dd * D + k] + xi_s[dd] * Wwoa[dd * D + k];
        xo_pre[(b * N_TOT + i) * D + k] = acc;
    }
}

// ---------------- Kernel 3: BatchNorm stats over 2048 rows
__global__ void k_stats(const float* __restrict__ xo_pre, float* __restrict__ stats) {
    int t = threadIdx.x;            // 1024 threads
    int d = t & 63, rc = t >> 6;    // 16 row-chunks
    float s = 0.f, q = 0.f;
    for (int r = rc; r < 2 * N_TOT; r += 16) {
        float v = xo_pre[r * D + d];
        s += v;
        q = fmaf(v, v, q);
    }
    __shared__ float s1[1024], s2[1024];
    s1[t] = s; s2[t] = q;
    __syncthreads();
    for (int st = 8; st >= 1; st >>= 1) {
        if (rc < st) { s1[t] += s1[t + st * 64]; s2[t] += s2[t + st * 64]; }
        __syncthreads();
    }
    if (t < D) {
        float mu = s1[t] * (1.f / 2048.f);
        float var = s2[t] * (1.f / 2048.f) - mu * mu;
        stats[t] = mu;
        stats[D + t] = rsqrtf(var + 1e-5f);
    }
}

// ---------------- Kernel 4: BN + SELU + pool scores
__global__ void k_norm(const float* __restrict__ xo_pre, const float* __restrict__ stats,
                       const float* __restrict__ gamma, const float* __restrict__ beta,
                       const float* __restrict__ Wp, const float* __restrict__ bp,
                       float* __restrict__ o_norm, float* __restrict__ scores) {
    int r = blockIdx.x;             // 0..2047
    int t = threadIdx.x;            // 64
    float v = xo_pre[r * D + t];
    v = (v - stats[t]) * stats[D + t] * gamma[t] + beta[t];
    const float kScale = 1.0507009873554805f, kAlpha = 1.6732632423543772f;
    v = (v > 0.f) ? kScale * v : kScale * kAlpha * expm1f(v);
    o_norm[r * D + t] = v;
    float pd = v * Wp[t];
#pragma unroll
    for (int off = 32; off >= 1; off >>= 1) pd += __shfl_xor(pd, off);
    if (t == 0) scores[r] = 1.f / (1.f + __expf(-(pd + bp[0])));
}

// ---------------- Kernel 5: top-k (k=256) via bitonic sort + gather
__global__ void k_pool(const float* __restrict__ o_norm, const float* __restrict__ scores,
                       float* __restrict__ out) {
    int bid = blockIdx.x;           // 0..3: b = bid>>1, half = bid&1
    int b = bid >> 1, half = bid & 1;
    int tid = threadIdx.x;          // 256
    __shared__ unsigned long long keys[N_HALF];

    for (int r = tid; r < N_HALF; r += 256) {
        float sc = scores[b * N_TOT + half * N_HALF + r];
        unsigned bits = __float_as_uint(sc);   // sigmoid > 0 -> monotone as uint
        keys[r] = ((unsigned long long)bits << 32) | (unsigned long long)(511 - r);
    }
    __syncthreads();

    // bitonic sort, descending (ties: larger (511-idx) first == smaller idx first)
    for (int k = 2; k <= N_HALF; k <<= 1) {
        for (int j = k >> 1; j > 0; j >>= 1) {
            for (int idx = tid; idx < N_HALF; idx += 256) {
                int l = idx ^ j;
                if (l > idx) {
                    unsigned long long a = keys[idx], c = keys[l];
                    bool sw = ((idx & k) == 0) ? (a < c) : (a > c);
                    if (sw) { keys[idx] = c; keys[l] = a; }
                }
            }
            __syncthreads();
        }
    }

    // gather: out row r = o_norm[src] * score[src]
    int kc = tid & 63;
    for (int r = tid >> 6; r < KPOOL; r += 4) {
        unsigned long long key = keys[r];
        int src = 511 - (int)(key & 0xFFFFFFFFull);
        float sc = __uint_as_float((unsigned)(key >> 32));
        out[((b * N_HALF) + half * KPOOL + r) * D + kc] =
            o_norm[((b * N_TOT) + half * N_HALF + src) * D + kc] * sc;
    }
}

extern "C" void kernel_launch(void* const* d_in, const int* in_sizes, int n_in,
                              void* d_out, int out_size, void* d_ws, size_t ws_size,
                              hipStream_t stream) {
    const float* x1   = (const float*)d_in[0];
    const float* x2   = (const float*)d_in[1];
    const float* W1   = (const float*)d_in[2];
    const float* b1   = (const float*)d_in[3];
    const float* W2   = (const float*)d_in[4];
    const float* b2   = (const float*)d_in[5];
    const float* Wa   = (const float*)d_in[6];
    const float* ba   = (const float*)d_in[7];
    // d_in[8..13]: WaM, baM, w11 @10 ... careful with order below
    const float* w11  = (const float*)d_in[10];
    const float* w22  = (const float*)d_in[11];
    const float* w12  = (const float*)d_in[12];
    const float* Wpa  = (const float*)d_in[14];
    const float* bpa  = (const float*)d_in[15];
    const float* Wwoa = (const float*)d_in[16];
    const float* bwoa = (const float*)d_in[17];
    const float* gamma= (const float*)d_in[22];
    const float* beta = (const float*)d_in[23];
    const float* Wp   = (const float*)d_in[24];
    const float* bp   = (const float*)d_in[25];
    float* out = (float*)d_out;

    char* ws = (char*)d_ws;
    float*          x_f    = (float*)(ws + 0);                 // 524288 B
    unsigned short* x_bf   = (unsigned short*)(ws + 524288);   // 262144 B
    float*          xo_pre = (float*)(ws + 786432);            // 524288 B
    float*          o_norm = (float*)(ws + 1310720);           // 524288 B
    float*          scores = (float*)(ws + 1835008);           // 8192 B
    float*          stats  = (float*)(ws + 1843200);           // 512 B

    hipLaunchKernelGGL(k_proj, dim3(2 * N_TOT), dim3(64), 0, stream,
                       x1, x2, W1, b1, W2, b2, x_f, x_bf);
    hipLaunchKernelGGL(k_attn, dim3(2 * N_TOT), dim3(256), 0, stream,
                       x_f, x_bf, Wa, ba, w11, w22, w12, Wpa, bpa, Wwoa, bwoa, xo_pre);
    hipLaunchKernelGGL(k_stats, dim3(1), dim3(1024), 0, stream, xo_pre, stats);
    hipLaunchKernelGGL(k_norm, dim3(2 * N_TOT), dim3(64), 0, stream,
                       xo_pre, stats, gamma, beta, Wp, bp, o_norm, scores);
    hipLaunchKernelGGL(k_pool, dim3(4), dim3(256), 0, stream, o_norm, scores, out);
}

// Round 2
// 128.905 us; speedup vs baseline: 1.4397x; 1.4397x over previous
//
#include <hip/hip_runtime.h>

typedef float f32x4 __attribute__((ext_vector_type(4)));
typedef short short8 __attribute__((ext_vector_type(8)));

#define N_TOT 1024
#define N_HALF 512
#define D 64
#define KPOOL 256

#if __has_builtin(__builtin_amdgcn_exp2f)
#define EXP2F(x) __builtin_amdgcn_exp2f(x)
#else
#define EXP2F(x) __expf((x) * 0.6931471805599453f)
#endif
#if __has_builtin(__builtin_amdgcn_rcpf)
#define RCPF(x) __builtin_amdgcn_rcpf(x)
#else
#define RCPF(x) (1.0f / (x))
#endif

__device__ __forceinline__ short f2bf(float v) {
    unsigned u = __float_as_uint(v);
    u += 0x7FFFu + ((u >> 16) & 1u);   // round-to-nearest-even
    return (short)(u >> 16);
}

// ---------------- Kernel 1: x = concat(x1@W1+b1, x2@W2+b2), fp32 + bf16 copies
__global__ void k_proj(const float* __restrict__ x1, const float* __restrict__ x2,
                       const float* __restrict__ W1, const float* __restrict__ b1,
                       const float* __restrict__ W2, const float* __restrict__ b2,
                       float* __restrict__ x_f, unsigned short* __restrict__ x_bf) {
    int r = blockIdx.x;               // 0..2047 (b*1024 + n)
    int b = r >> 10, n = r & 1023;
    const float *src, *W, *bias;
    if (n < N_HALF) { src = x1 + (b * N_HALF + n) * D;            W = W1; bias = b1; }
    else            { src = x2 + (b * N_HALF + (n - N_HALF)) * D; W = W2; bias = b2; }
    __shared__ float row[D];
    int t = threadIdx.x;
    row[t] = src[t];
    __syncthreads();
    float acc = bias[t];
#pragma unroll
    for (int d = 0; d < D; ++d) acc = fmaf(row[d], W[d * D + t], acc);
    x_f[r * D + t] = acc;
    x_bf[r * D + t] = (unsigned short)f2bf(acc);
}

// ---------------- Kernel 2: per (b,i): scores over all j, softmax, agg, out-proj
__global__ void __launch_bounds__(256)
k_attn(const float* __restrict__ x_f, const unsigned short* __restrict__ x_bf,
       const float* __restrict__ Wa, const float* __restrict__ ba,
       const float* __restrict__ w11, const float* __restrict__ w22,
       const float* __restrict__ w12,
       const float* __restrict__ Wpa, const float* __restrict__ bpa,
       const float* __restrict__ Wwoa, const float* __restrict__ bwoa,
       float* __restrict__ xo_pre) {
    int bid = blockIdx.x;             // 0..2047
    int b = bid >> 10, i = bid & 1023;
    int tid = threadIdx.x;
    int l = tid & 63, wv = tid >> 6;
    int kc = l & 15, dg = l >> 4;

    __shared__ float xi_s[D];
    __shared__ float ssc[N_TOT];
    __shared__ float red[8];
    __shared__ f32x4 aggred4[16][16];
    __shared__ float aggv[D];
    __shared__ float denom_s;

    if (tid < D) xi_s[tid] = x_f[(b * N_TOT + i) * D + tid];
    __syncthreads();

    const float C2 = 2.885390081777927f;      // 2*log2(e)
    const float LOG2E = 1.4426950408889634f;

    // wave wv handles jt in [wv*16, wv*16+16) -> j < 512 iff wv < 2 (wave-uniform)
    const float* wvec = (i < N_HALF) ? ((wv < 2) ? w11 : w12)
                                     : ((wv < 2) ? w12 : w22);

    // B fragments: B[d][k] = x_i[d] * Wa[d][k] in bf16; lane holds col kc, 8 d's at dg*8 (+32)
    short8 bfrag[4][2];
    float bac[4], wm2[4];
    float wsum = 0.f;
#pragma unroll
    for (int kt = 0; kt < 4; ++kt) {
        int kcol = kt * 16 + kc;
        bac[kt] = ba[kcol] * C2;
        float w = wvec[kcol];
        wm2[kt] = -2.f * w;
        wsum += w;
#pragma unroll
        for (int m = 0; m < 2; ++m) {
            short8 f;
#pragma unroll
            for (int e = 0; e < 8; ++e) {
                int d = m * 32 + dg * 8 + e;
                f[e] = f2bf(xi_s[d] * Wa[d * D + kcol]);
            }
            bfrag[kt][m] = f;
        }
    }

    // scoring: s[j] = sum_k w_k * tanh(pre_jk);  tanh = 1 - 2*rcp(exp2(pre*2log2e)+1)
    // fused: exp(s) written to ssc + running denom
    const unsigned short* xb_b = x_bf + b * N_TOT * D;
    float lsum = 0.f;
    for (int jt = wv * 16; jt < wv * 16 + 16; ++jt) {
        const unsigned short* arow = xb_b + (jt * 16 + kc) * D + dg * 8;
        short8 a0 = *reinterpret_cast<const short8*>(arow);
        short8 a1 = *reinterpret_cast<const short8*>(arow + 32);
        f32x4 acc[4];
#pragma unroll
        for (int kt = 0; kt < 4; ++kt) {
            f32x4 z = {0.f, 0.f, 0.f, 0.f};
            z = __builtin_amdgcn_mfma_f32_16x16x32_bf16(a0, bfrag[kt][0], z, 0, 0, 0);
            z = __builtin_amdgcn_mfma_f32_16x16x32_bf16(a1, bfrag[kt][1], z, 0, 0, 0);
            acc[kt] = z;
        }
#pragma unroll
        for (int r = 0; r < 4; ++r) {
            float part = wsum;
#pragma unroll
            for (int kt = 0; kt < 4; ++kt) {
                float e2 = EXP2F(fmaf(acc[kt][r], C2, bac[kt]));
                float rc = RCPF(e2 + 1.f);
                part = fmaf(wm2[kt], rc, part);
            }
            part += __shfl_xor(part, 1);
            part += __shfl_xor(part, 2);
            part += __shfl_xor(part, 4);
            part += __shfl_xor(part, 8);
            if (kc == 0) {
                float e = EXP2F(part * LOG2E);   // no max-shift: |s| <= sum|w| ~ 10
                ssc[jt * 16 + dg * 4 + r] = e;
                lsum += e;
            }
        }
    }
    // block reduce of denom (only kc==0 lanes nonzero)
#pragma unroll
    for (int off = 32; off >= 1; off >>= 1) lsum += __shfl_xor(lsum, off);
    if (l == 0) red[wv] = lsum;
    __syncthreads();
    if (tid == 0) denom_s = red[0] + red[1] + red[2] + red[3];

    // agg[d] = sum_j e_j * x[j][d]   (float4 loads, 16-way j split)
    int dq = tid & 15, c = tid >> 4;
    const f32x4* xf4 = reinterpret_cast<const f32x4*>(x_f + b * N_TOT * D);
    __syncthreads();
    f32x4 a4 = {0.f, 0.f, 0.f, 0.f};
    int j0 = c * 64;
#pragma unroll 4
    for (int jj = 0; jj < 64; ++jj) {
        float w = ssc[j0 + jj];
        f32x4 v = xf4[(j0 + jj) * 16 + dq];
        a4 += v * w;
    }
    aggred4[c][dq] = a4;
    __syncthreads();
    float denom = denom_s;
    if (tid < D) {
        float s = 0.f;
#pragma unroll
        for (int c2 = 0; c2 < 16; ++c2) {
            f32x4 v = aggred4[c2][tid >> 2];
            s += v[tid & 3];
        }
        aggv[tid] = s / denom;
    }
    __syncthreads();

    // xo = agg@Wpa + bpa + x_i@Wwoa + bwoa
    if (tid < D) {
        int k = tid;
        float acc = bpa[k] + bwoa[k];
#pragma unroll 8
        for (int dd = 0; dd < D; ++dd)
            acc += aggv[dd] * Wpa[dd * D + k] + xi_s[dd] * Wwoa[dd * D + k];
        xo_pre[(b * N_TOT + i) * D + k] = acc;
    }
}

// ---------------- Kernel 3: BatchNorm stats over 2048 rows (float4)
__global__ void __launch_bounds__(1024) k_stats(const float* __restrict__ xo_pre,
                                                float* __restrict__ stats) {
    int t = threadIdx.x;            // 1024 threads
    int dq = t & 15, rc = t >> 4;   // 64 row-chunks
    const f32x4* p = (const f32x4*)xo_pre;
    f32x4 s = {0.f, 0.f, 0.f, 0.f}, q = {0.f, 0.f, 0.f, 0.f};
    for (int r = rc; r < 2 * N_TOT; r += 64) {
        f32x4 v = p[r * 16 + dq];
        s += v;
        q += v * v;
    }
    __shared__ f32x4 S[64][16];
    __shared__ f32x4 Q[64][16];
    S[rc][dq] = s; Q[rc][dq] = q;
    __syncthreads();
    for (int st = 32; st >= 1; st >>= 1) {
        if (rc < st) { S[rc][dq] += S[rc + st][dq]; Q[rc][dq] += Q[rc + st][dq]; }
        __syncthreads();
    }
    if (t < D) {
        float mu  = S[0][t >> 2][t & 3] * (1.f / 2048.f);
        float ex2 = Q[0][t >> 2][t & 3] * (1.f / 2048.f);
        stats[t] = mu;
        stats[D + t] = rsqrtf(ex2 - mu * mu + 1e-5f);
    }
}

// ---------------- Kernel 4: BN + SELU + pool scores (4 rows/block)
__global__ void k_norm(const float* __restrict__ xo_pre, const float* __restrict__ stats,
                       const float* __restrict__ gamma, const float* __restrict__ beta,
                       const float* __restrict__ Wp, const float* __restrict__ bp,
                       float* __restrict__ o_norm, float* __restrict__ scores) {
    int r = blockIdx.x * 4 + (threadIdx.x >> 6);  // 0..2047
    int t = threadIdx.x & 63;
    float v = xo_pre[r * D + t];
    v = (v - stats[t]) * stats[D + t] * gamma[t] + beta[t];
    const float kScale = 1.0507009873554805f, kAlpha = 1.6732632423543772f;
    v = (v > 0.f) ? kScale * v : kScale * kAlpha * expm1f(v);
    o_norm[r * D + t] = v;
    float pd = v * Wp[t];
#pragma unroll
    for (int off = 32; off >= 1; off >>= 1) pd += __shfl_xor(pd, off);
    if (t == 0) scores[r] = 1.f / (1.f + __expf(-(pd + bp[0])));
}

// ---------------- Kernel 5: top-k (k=256) via bitonic sort + gather
__global__ void k_pool(const float* __restrict__ o_norm, const float* __restrict__ scores,
                       float* __restrict__ out) {
    int bid = blockIdx.x;           // 0..3: b = bid>>1, half = bid&1
    int b = bid >> 1, half = bid & 1;
    int tid = threadIdx.x;          // 256
    __shared__ unsigned long long keys[N_HALF];

    for (int r = tid; r < N_HALF; r += 256) {
        float sc = scores[b * N_TOT + half * N_HALF + r];
        unsigned bits = __float_as_uint(sc);   // sigmoid > 0 -> monotone as uint
        keys[r] = ((unsigned long long)bits << 32) | (unsigned long long)(511 - r);
    }
    __syncthreads();

    // bitonic sort, descending (ties: larger (511-idx) first == smaller idx first)
    for (int k = 2; k <= N_HALF; k <<= 1) {
        for (int j = k >> 1; j > 0; j >>= 1) {
            for (int idx = tid; idx < N_HALF; idx += 256) {
                int l = idx ^ j;
                if (l > idx) {
                    unsigned long long a = keys[idx], c = keys[l];
                    bool sw = ((idx & k) == 0) ? (a < c) : (a > c);
                    if (sw) { keys[idx] = c; keys[l] = a; }
                }
            }
            __syncthreads();
        }
    }

    // gather: out row r = o_norm[src] * score[src]
    int kc = tid & 63;
    for (int r = tid >> 6; r < KPOOL; r += 4) {
        unsigned long long key = keys[r];
        int src = 511 - (int)(key & 0xFFFFFFFFull);
        float sc = __uint_as_float((unsigned)(key >> 32));
        out[((b * N_HALF) + half * KPOOL + r) * D + kc] =
            o_norm[((b * N_TOT) + half * N_HALF + src) * D + kc] * sc;
    }
}

extern "C" void kernel_launch(void* const* d_in, const int* in_sizes, int n_in,
                              void* d_out, int out_size, void* d_ws, size_t ws_size,
                              hipStream_t stream) {
    const float* x1   = (const float*)d_in[0];
    const float* x2   = (const float*)d_in[1];
    const float* W1   = (const float*)d_in[2];
    const float* b1   = (const float*)d_in[3];
    const float* W2   = (const float*)d_in[4];
    const float* b2   = (const float*)d_in[5];
    const float* Wa   = (const float*)d_in[6];
    const float* ba   = (const float*)d_in[7];
    const float* w11  = (const float*)d_in[10];
    const float* w22  = (const float*)d_in[11];
    const float* w12  = (const float*)d_in[12];
    const float* Wpa  = (const float*)d_in[14];
    const float* bpa  = (const float*)d_in[15];
    const float* Wwoa = (const float*)d_in[16];
    const float* bwoa = (const float*)d_in[17];
    const float* gamma= (const float*)d_in[22];
    const float* beta = (const float*)d_in[23];
    const float* Wp   = (const float*)d_in[24];
    const float* bp   = (const float*)d_in[25];
    float* out = (float*)d_out;

    char* ws = (char*)d_ws;
    float*          x_f    = (float*)(ws + 0);                 // 524288 B
    unsigned short* x_bf   = (unsigned short*)(ws + 524288);   // 262144 B
    float*          xo_pre = (float*)(ws + 786432);            // 524288 B
    float*          o_norm = (float*)(ws + 1310720);           // 524288 B
    float*          scores = (float*)(ws + 1835008);           // 8192 B
    float*          stats  = (float*)(ws + 1843200);           // 512 B

    hipLaunchKernelGGL(k_proj, dim3(2 * N_TOT), dim3(64), 0, stream,
                       x1, x2, W1, b1, W2, b2, x_f, x_bf);
    hipLaunchKernelGGL(k_attn, dim3(2 * N_TOT), dim3(256), 0, stream,
                       x_f, x_bf, Wa, ba, w11, w22, w12, Wpa, bpa, Wwoa, bwoa, xo_pre);
    hipLaunchKernelGGL(k_stats, dim3(1), dim3(1024), 0, stream, xo_pre, stats);
    hipLaunchKernelGGL(k_norm, dim3(512), dim3(256), 0, stream,
                       xo_pre, stats, gamma, beta, Wp, bp, o_norm, scores);
    hipLaunchKernelGGL(k_pool, dim3(4), dim3(256), 0, stream, o_norm, scores, out);
}

// Round 4
// 117.704 us; speedup vs baseline: 1.5767x; 1.0952x over previous
//
#include <hip/hip_runtime.h>

typedef float f32x4 __attribute__((ext_vector_type(4)));
typedef short short8 __attribute__((ext_vector_type(8)));

#define N_TOT 1024
#define N_HALF 512
#define D 64
#define KPOOL 256

#if __has_builtin(__builtin_amdgcn_exp2f)
#define EXP2F(x) __builtin_amdgcn_exp2f(x)
#else
#define EXP2F(x) __expf((x) * 0.6931471805599453f)
#endif
#if __has_builtin(__builtin_amdgcn_rcpf)
#define RCPF(x) __builtin_amdgcn_rcpf(x)
#else
#define RCPF(x) (1.0f / (x))
#endif

__device__ __forceinline__ short f2bf(float v) {
    unsigned u = __float_as_uint(v);
    u += 0x7FFFu + ((u >> 16) & 1u);   // round-to-nearest-even
    return (short)(u >> 16);
}

// ---------------- Kernel 1: x = concat(x1@W1+b1, x2@W2+b2), fp32 + bf16 copies
__global__ void k_proj(const float* __restrict__ x1, const float* __restrict__ x2,
                       const float* __restrict__ W1, const float* __restrict__ b1,
                       const float* __restrict__ W2, const float* __restrict__ b2,
                       float* __restrict__ x_f, unsigned short* __restrict__ x_bf) {
    int r = blockIdx.x;               // 0..2047 (b*1024 + n)
    int b = r >> 10, n = r & 1023;
    const float *src, *W, *bias;
    if (n < N_HALF) { src = x1 + (b * N_HALF + n) * D;            W = W1; bias = b1; }
    else            { src = x2 + (b * N_HALF + (n - N_HALF)) * D; W = W2; bias = b2; }
    __shared__ float row[D];
    int t = threadIdx.x;
    row[t] = src[t];
    __syncthreads();
    float acc = bias[t];
#pragma unroll
    for (int d = 0; d < D; ++d) acc = fmaf(row[d], W[d * D + t], acc);
    x_f[r * D + t] = acc;
    x_bf[r * D + t] = (unsigned short)f2bf(acc);
}

// ---------------- Kernel 2: scores, upper triangle only (s symmetric), E=exp(s)
__global__ void __launch_bounds__(256)
k_score(const float* __restrict__ x_f, const unsigned short* __restrict__ x_bf,
        const float* __restrict__ Wa, const float* __restrict__ ba,
        const float* __restrict__ w11, const float* __restrict__ w22,
        const float* __restrict__ w12, float* __restrict__ E) {
    int bid = blockIdx.x;             // 0..2047
    int b = bid >> 10, n = bid & 1023;
    // work-balance swizzle: per-CU (bid mod 256) total triangle work is constant
    int q = n >> 8, c = n & 255;
    int i = (q << 8) | ((q & 1) ? (255 - c) : c);
    int tid = threadIdx.x;
    int l = tid & 63, wv = tid >> 6;
    int kc = l & 15, dg = l >> 4;

    __shared__ float xi_s[D];
    if (tid < D) xi_s[tid] = x_f[(b * N_TOT + i) * D + tid];
    __syncthreads();

    const float C2 = 2.885390081777927f;      // 2*log2(e)
    const float LOG2E = 1.4426950408889634f;

    const float* wTop = (i < N_HALF) ? w11 : w12;   // weight when j < 512
    const float* wBot = (i < N_HALF) ? w12 : w22;   // weight when j >= 512

    // B fragments: B[d][k] = x_i[d] * Wa[d][k] in bf16
    short8 bfrag[4][2];
    float bac[4], wm2A[4], wm2B[4];
    float wsumA = 0.f, wsumB = 0.f;
#pragma unroll
    for (int kt = 0; kt < 4; ++kt) {
        int kcol = kt * 16 + kc;
        bac[kt] = ba[kcol] * C2;
        float wA = wTop[kcol], wB = wBot[kcol];
        wm2A[kt] = -2.f * wA; wm2B[kt] = -2.f * wB;
        wsumA += wA; wsumB += wB;
#pragma unroll
        for (int m = 0; m < 2; ++m) {
            short8 f;
#pragma unroll
            for (int e = 0; e < 8; ++e) {
                int d = m * 32 + dg * 8 + e;
                f[e] = f2bf(xi_s[d] * Wa[d * D + kcol]);
            }
            bfrag[kt][m] = f;
        }
    }

    const unsigned short* xb_b = x_bf + b * N_TOT * D;
    float* Eb = E + ((size_t)b << 20);
    int jt0 = i >> 4;
    for (int jt = jt0 + wv; jt < 64; jt += 4) {
        const unsigned short* arow = xb_b + (jt * 16 + kc) * D + dg * 8;
        short8 a0 = *reinterpret_cast<const short8*>(arow);
        short8 a1 = *reinterpret_cast<const short8*>(arow + 32);
        f32x4 acc[4];
#pragma unroll
        for (int kt = 0; kt < 4; ++kt) {
            f32x4 z = {0.f, 0.f, 0.f, 0.f};
            z = __builtin_amdgcn_mfma_f32_16x16x32_bf16(a0, bfrag[kt][0], z, 0, 0, 0);
            z = __builtin_amdgcn_mfma_f32_16x16x32_bf16(a1, bfrag[kt][1], z, 0, 0, 0);
            acc[kt] = z;
        }
        bool top = (jt < 32);
        float wsum_t = top ? wsumA : wsumB;
#pragma unroll
        for (int r = 0; r < 4; ++r) {
            float part = wsum_t;
#pragma unroll
            for (int kt = 0; kt < 4; ++kt) {
                float e2 = EXP2F(fmaf(acc[kt][r], C2, bac[kt]));
                float rcv = RCPF(e2 + 1.f);
                part = fmaf(top ? wm2A[kt] : wm2B[kt], rcv, part);
            }
            part += __shfl_xor(part, 1);
            part += __shfl_xor(part, 2);
            part += __shfl_xor(part, 4);
            part += __shfl_xor(part, 8);
            if (kc == 0) {
                int j = jt * 16 + dg * 4 + r;
                if (j >= i) {
                    float e = EXP2F(part * LOG2E);   // |s| <= sum|w| ~ 10, no max-shift
                    Eb[(size_t)i * N_TOT + j] = e;
                    if (j > i) Eb[(size_t)j * N_TOT + i] = e;
                }
            }
        }
    }
}

// ---------------- Kernel 3: colsum[j] = sum_i E[i,j]; by symmetry == rowsum_j. rinv = 1/colsum
__global__ void k_colsum(const float* __restrict__ E, float* __restrict__ rinv) {
    int b = blockIdx.x >> 5, jc = blockIdx.x & 31;   // 32 j-chunks of 32
    int tid = threadIdx.x;                           // 256
    int jl = tid & 31, seg = tid >> 5;               // 8 i-segments of 128
    int j = jc * 32 + jl;
    const float* Eb = E + ((size_t)b << 20);
    float s = 0.f;
    int i0 = seg * 128;
    for (int ii = 0; ii < 128; ++ii) s += Eb[(size_t)(i0 + ii) * N_TOT + j];
    __shared__ float red[8][32];
    red[seg][jl] = s;
    __syncthreads();
    if (seg == 0) {
        float t = 0.f;
#pragma unroll
        for (int qq = 0; qq < 8; ++qq) t += red[qq][jl];
        rinv[b * N_TOT + j] = 1.f / t;
    }
}

// ---------------- Kernel 4: agg[i] = rinv[i] * (E[i,:] @ x), xo = agg@Wpa + x@Wwoa + biases, BN partials
__global__ void __launch_bounds__(1024)
k_agg(const float* __restrict__ E, const float* __restrict__ rinv,
      const float* __restrict__ x_f,
      const float* __restrict__ Wpa, const float* __restrict__ bpa,
      const float* __restrict__ Wwoa, const float* __restrict__ bwoa,
      float* __restrict__ xo_pre, float* __restrict__ partials) {
    int b = blockIdx.x >> 6, it = blockIdx.x & 63;   // 64 i-tiles of 16
    int tid = threadIdx.x;
    int il = tid >> 6, d = tid & 63;
    int i = it * 16 + il;
    int iu = __builtin_amdgcn_readfirstlane(i);      // wave-uniform row -> scalar loads
    const float* Erow = E + ((size_t)b << 20) + (size_t)iu * N_TOT;
    const float* xB = x_f + (size_t)b * N_TOT * D;
    float acc = 0.f;
#pragma unroll 8
    for (int j = 0; j < N_TOT; ++j)
        acc = fmaf(Erow[j], xB[j * D + d], acc);
    float ri = rinv[b * N_TOT + iu];

    __shared__ float aggL[16][D];
    __shared__ float xiL[16][D];
    aggL[il][d] = acc * ri;
    xiL[il][d] = xB[(size_t)i * D + d];
    __syncthreads();
    int k = d;
    float xo = bpa[k] + bwoa[k];
#pragma unroll 8
    for (int dd = 0; dd < D; ++dd)
        xo += aggL[il][dd] * Wpa[dd * D + k] + xiL[il][dd] * Wwoa[dd * D + k];
    xo_pre[((size_t)b * N_TOT + i) * D + k] = xo;

    // BN partial sums for this 16-row tile
    __syncthreads();
    aggL[il][k] = xo;
    xiL[il][k] = xo * xo;
    __syncthreads();
    if (il == 0) {
        float s = 0.f, qs = 0.f;
#pragma unroll
        for (int m = 0; m < 16; ++m) { s += aggL[m][k]; qs += xiL[m][k]; }
        partials[blockIdx.x * 128 + k] = s;
        partials[blockIdx.x * 128 + 64 + k] = qs;
    }
}

// ---------------- Kernel 5: finish BN stats (512 threads: 4 block-groups x 128)
__global__ void k_stats2(const float* __restrict__ partials, float* __restrict__ stats) {
    int t = threadIdx.x;            // 512
    int g = t >> 7;                 // 0..3 : 32 blocks each
    int f128 = t & 127;             // which*64 + f
    float s = 0.f;
    for (int blk = g * 32; blk < g * 32 + 32; ++blk) s += partials[blk * 128 + f128];
    __shared__ float SQ[4][128];
    SQ[g][f128] = s;
    __syncthreads();
    if (t < 128) {
        float tot = SQ[0][t] + SQ[1][t] + SQ[2][t] + SQ[3][t];
        SQ[0][t] = tot;
    }
    __syncthreads();
    if (t < D) {
        float mu = SQ[0][t] * (1.f / 2048.f);
        float ex2 = SQ[0][64 + t] * (1.f / 2048.f);
        stats[t] = mu;
        stats[D + t] = rsqrtf(ex2 - mu * mu + 1e-5f);
    }
}

// ---------------- Kernel 6: BN + SELU + pool scores (4 rows/block)
__global__ void k_norm(const float* __restrict__ xo_pre, const float* __restrict__ stats,
                       const float* __restrict__ gamma, const float* __restrict__ beta,
                       const float* __restrict__ Wp, const float* __restrict__ bp,
                       float* __restrict__ o_norm, float* __restrict__ scores) {
    int r = blockIdx.x * 4 + (threadIdx.x >> 6);  // 0..2047
    int t = threadIdx.x & 63;
    float v = xo_pre[r * D + t];
    v = (v - stats[t]) * stats[D + t] * gamma[t] + beta[t];
    const float kScale = 1.0507009873554805f, kAlpha = 1.6732632423543772f;
    v = (v > 0.f) ? kScale * v : kScale * kAlpha * expm1f(v);
    o_norm[r * D + t] = v;
    float pd = v * Wp[t];
#pragma unroll
    for (int off = 32; off >= 1; off >>= 1) pd += __shfl_xor(pd, off);
    if (t == 0) scores[r] = 1.f / (1.f + __expf(-(pd + bp[0])));
}

// ---------------- Kernel 7: top-k (k=256) via exact ranking + gather
__global__ void k_pool(const float* __restrict__ o_norm, const float* __restrict__ scores,
                       float* __restrict__ out) {
    int b = blockIdx.x >> 1, half = blockIdx.x & 1;
    int tid = threadIdx.x;          // 256
    __shared__ float sc_s[N_HALF];
    __shared__ unsigned long long keys[N_HALF];
    __shared__ unsigned short map[KPOOL];

    for (int r = tid; r < N_HALF; r += 256) {
        float sc = scores[b * N_TOT + half * N_HALF + r];
        sc_s[r] = sc;
        // sigmoid > 0 -> float bits monotone as uint; ties: smaller idx wins
        keys[r] = ((unsigned long long)__float_as_uint(sc) << 10) | (unsigned)(511 - r);
    }
    __syncthreads();
    unsigned long long k1 = keys[tid], k2 = keys[tid + 256];
    int c1 = 0, c2 = 0;
    for (int qq = 0; qq < N_HALF; ++qq) {
        unsigned long long kq = keys[qq];
        c1 += (kq > k1) ? 1 : 0;
        c2 += (kq > k2) ? 1 : 0;
    }
    if (c1 < KPOOL) map[c1] = (unsigned short)tid;
    if (c2 < KPOOL) map[c2] = (unsigned short)(tid + 256);
    __syncthreads();
    int d = tid & 63;
    for (int rr = tid >> 6; rr < KPOOL; rr += 4) {
        int src = map[rr];
        out[(size_t)(b * N_HALF + half * KPOOL + rr) * D + d] =
            o_norm[(size_t)(b * N_TOT + half * N_HALF + src) * D + d] * sc_s[src];
    }
}

extern "C" void kernel_launch(void* const* d_in, const int* in_sizes, int n_in,
                              void* d_out, int out_size, void* d_ws, size_t ws_size,
                              hipStream_t stream) {
    const float* x1   = (const float*)d_in[0];
    const float* x2   = (const float*)d_in[1];
    const float* W1   = (const float*)d_in[2];
    const float* b1   = (const float*)d_in[3];
    const float* W2   = (const float*)d_in[4];
    const float* b2   = (const float*)d_in[5];
    const float* Wa   = (const float*)d_in[6];
    const float* ba   = (const float*)d_in[7];
    const float* w11  = (const float*)d_in[10];
    const float* w22  = (const float*)d_in[11];
    const float* w12  = (const float*)d_in[12];
    const float* Wpa  = (const float*)d_in[14];
    const float* bpa  = (const float*)d_in[15];
    const float* Wwoa = (const float*)d_in[16];
    const float* bwoa = (const float*)d_in[17];
    const float* gamma= (const float*)d_in[22];
    const float* beta = (const float*)d_in[23];
    const float* Wp   = (const float*)d_in[24];
    const float* bp   = (const float*)d_in[25];
    float* out = (float*)d_out;

    char* ws = (char*)d_ws;
    float*          x_f     = (float*)(ws + 0);                  // 524288
    unsigned short* x_bf    = (unsigned short*)(ws + 524288);    // 262144
    float*          E       = (float*)(ws + 786432);             // 8388608
    float*          xo_pre  = (float*)(ws + 9175040);            // 524288
    float*          o_norm  = (float*)(ws + 9699328);            // 524288
    float*          scores  = (float*)(ws + 10223616);           // 8192
    float*          partials= (float*)(ws + 10231808);           // 65536
    float*          stats   = (float*)(ws + 10297344);           // 512
    float*          rinv    = (float*)(ws + 10297856);           // 8192

    hipLaunchKernelGGL(k_proj, dim3(2 * N_TOT), dim3(64), 0, stream,
                       x1, x2, W1, b1, W2, b2, x_f, x_bf);
    hipLaunchKernelGGL(k_score, dim3(2 * N_TOT), dim3(256), 0, stream,
                       x_f, x_bf, Wa, ba, w11, w22, w12, E);
    hipLaunchKernelGGL(k_colsum, dim3(64), dim3(256), 0, stream, E, rinv);
    hipLaunchKernelGGL(k_agg, dim3(128), dim3(1024), 0, stream,
                       E, rinv, x_f, Wpa, bpa, Wwoa, bwoa, xo_pre, partials);
    hipLaunchKernelGGL(k_stats2, dim3(1), dim3(512), 0, stream, partials, stats);
    hipLaunchKernelGGL(k_norm, dim3(512), dim3(256), 0, stream,
                       xo_pre, stats, gamma, beta, Wp, bp, o_norm, scores);
    hipLaunchKernelGGL(k_pool, dim3(4), dim3(256), 0, stream, o_norm, scores, out);
}